// Round 1
// baseline (250.780 us; speedup 1.0000x reference)
//
#include <hip/hip_runtime.h>
#include <stdint.h>

typedef __attribute__((ext_vector_type(8))) __bf16 bf16x8;
typedef __attribute__((ext_vector_type(4))) float f32x4;
typedef __attribute__((ext_vector_type(8))) short short8;

#define MFMA(a, b, c) __builtin_amdgcn_mfma_f32_16x16x32_bf16((a), (b), (c), 0, 0, 0)

constexpr int DIMC  = 1024;
constexpr int HEADS = 16;
constexpr int HD    = 64;
constexpr int BATCH = 4;
constexpr int SEQ   = 1370;
constexpr int MROWS = BATCH * SEQ;      // 5480
constexpr int NPAD  = 1408;             // 22*64
constexpr float QK_SCALE = 0.125f;      // 64^-0.5

__device__ __forceinline__ unsigned short f2bf(float f) {
    union { float f; unsigned int u; } v; v.f = f;
    unsigned int r = (v.u + 0x7FFFu + ((v.u >> 16) & 1u)) >> 16;
    return (unsigned short)r;
}

// ---------------- cast x -> bf16 (8 elems/thread) ----------------
__global__ void cast_x_kernel(const float* __restrict__ x, unsigned short* __restrict__ xb, int nvec) {
    int i = blockIdx.x * blockDim.x + threadIdx.x;
    if (i >= nvec) return;
    f32x4 a = reinterpret_cast<const f32x4*>(x)[2 * i];
    f32x4 b = reinterpret_cast<const f32x4*>(x)[2 * i + 1];
    short8 o;
    o[0] = (short)f2bf(a[0]); o[1] = (short)f2bf(a[1]);
    o[2] = (short)f2bf(a[2]); o[3] = (short)f2bf(a[3]);
    o[4] = (short)f2bf(b[0]); o[5] = (short)f2bf(b[1]);
    o[6] = (short)f2bf(b[2]); o[7] = (short)f2bf(b[3]);
    reinterpret_cast<short8*>(xb)[i] = o;
}

// ------------- cast + transpose weights: in[R][C] f32 -> out[C][R] bf16 -------------
__global__ __launch_bounds__(256) void transpose_cast_kernel(const float* __restrict__ in,
                                                             unsigned short* __restrict__ out,
                                                             int R, int C) {
    __shared__ float tile[32][33];
    int tx = threadIdx.x & 31, ty = threadIdx.x >> 5;   // 32 x 8
    int cbase = blockIdx.x * 32, rbase = blockIdx.y * 32;
#pragma unroll
    for (int rr = 0; rr < 4; ++rr) {
        int r = ty + rr * 8;
        tile[r][tx] = in[(size_t)(rbase + r) * C + cbase + tx];
    }
    __syncthreads();
#pragma unroll
    for (int rr = 0; rr < 4; ++rr) {
        int cr = ty + rr * 8;
        out[(size_t)(cbase + cr) * R + rbase + tx] = f2bf(tile[tx][cr]);
    }
}

// ------------- zero the vT column pad [SEQ..NPAD) so masked P*garbage can't NaN -------------
__global__ void zero_vpad_kernel(unsigned short* __restrict__ vTg) {
    int idx = blockIdx.x * blockDim.x + threadIdx.x;
    const int padw = NPAD - SEQ;                 // 38
    const int total = 64 * 64 * padw;
    if (idx >= total) return;
    int col = SEQ + idx % padw;
    int rowflat = idx / padw;                    // bh*64 + d
    vTg[(size_t)rowflat * NPAD + col] = 0;
}

// ---------------- bf16 GEMM: C[M,N] = A[M,K] * Bt[N,K]^T (+bias), fused epilogues ----------------
// EPI 0: scatter into q (scaled), k, vT buffers.  EPI 1: fp32 output + bias.
template <int EPI>
__global__ __launch_bounds__(256) void gemm_bt_kernel(const unsigned short* __restrict__ A,
                                                      const unsigned short* __restrict__ Bt,
                                                      int M, int N, int K,
                                                      const float* __restrict__ bias,
                                                      unsigned short* __restrict__ qg,
                                                      unsigned short* __restrict__ kg,
                                                      unsigned short* __restrict__ vTg,
                                                      float* __restrict__ outf) {
    __shared__ unsigned short As[128 * 40];   // stride 40 ushorts = 80B (16B aligned, 2-way banks)
    __shared__ unsigned short Bs[128 * 40];
    const int tid = threadIdx.x;
    const int l = tid & 63, w = tid >> 6;
    const int wr = w >> 1, wc = w & 1;
    const int lm = l & 15, lk = l >> 4;
    const int brow = blockIdx.y * 128, bcol = blockIdx.x * 128;

    f32x4 acc[4][4];
#pragma unroll
    for (int i = 0; i < 4; ++i)
#pragma unroll
        for (int j = 0; j < 4; ++j) acc[i][j] = f32x4{0.f, 0.f, 0.f, 0.f};

    const int nkt = K >> 5;
    for (int kt = 0; kt < nkt; ++kt) {
#pragma unroll
        for (int rr = 0; rr < 2; ++rr) {
            int flat = rr * 256 + tid;           // 0..511
            int row = flat >> 2;                 // 0..127
            int c8 = (flat & 3) << 3;            // 0,8,16,24
            int ga = min(brow + row, M - 1);
            short8 va = *reinterpret_cast<const short8*>(&A[(size_t)ga * K + kt * 32 + c8]);
            *reinterpret_cast<short8*>(&As[row * 40 + c8]) = va;
            int gb = bcol + row;                 // N is a multiple of 128
            short8 vb = *reinterpret_cast<const short8*>(&Bt[(size_t)gb * K + kt * 32 + c8]);
            *reinterpret_cast<short8*>(&Bs[row * 40 + c8]) = vb;
        }
        __syncthreads();
        bf16x8 af[4], bfr[4];
#pragma unroll
        for (int i = 0; i < 4; ++i)
            af[i] = *reinterpret_cast<const bf16x8*>(&As[(wr * 64 + i * 16 + lm) * 40 + lk * 8]);
#pragma unroll
        for (int j = 0; j < 4; ++j)
            bfr[j] = *reinterpret_cast<const bf16x8*>(&Bs[(wc * 64 + j * 16 + lm) * 40 + lk * 8]);
#pragma unroll
        for (int i = 0; i < 4; ++i)
#pragma unroll
            for (int j = 0; j < 4; ++j)
                acc[i][j] = MFMA(af[i], bfr[j], acc[i][j]);
        __syncthreads();
    }

    // epilogue: C layout per fragment -> row=(lk*4+r), col=lm
#pragma unroll
    for (int i = 0; i < 4; ++i) {
        int mbase = brow + wr * 64 + i * 16 + lk * 4;
#pragma unroll
        for (int j = 0; j < 4; ++j) {
            int col = bcol + wc * 64 + j * 16 + lm;
            float bv = bias[col];
#pragma unroll
            for (int r = 0; r < 4; ++r) {
                int m = mbase + r;
                if (m >= M) continue;
                float val = acc[i][j][r] + bv;
                if constexpr (EPI == 0) {
                    int which = col >> 10;          // 0:q 1:k 2:v
                    int head = (col >> 6) & 15;
                    int d = col & 63;
                    int b = m / SEQ;
                    int nseq = m - b * SEQ;
                    int bh = b * HEADS + head;
                    if (which == 0) {
                        qg[((size_t)bh * SEQ + nseq) * HD + d] = f2bf(val * QK_SCALE);
                    } else if (which == 1) {
                        kg[((size_t)bh * SEQ + nseq) * HD + d] = f2bf(val);
                    } else {
                        vTg[((size_t)bh * HD + d) * NPAD + nseq] = f2bf(val);
                    }
                } else {
                    outf[(size_t)m * DIMC + col] = val;
                }
            }
        }
    }
}

// ---------------- flash attention: 64 q-rows / block, KV tiles of 64 ----------------
__global__ __launch_bounds__(256) void attn_kernel(const unsigned short* __restrict__ qg,
                                                   const unsigned short* __restrict__ kg,
                                                   const unsigned short* __restrict__ vTg,
                                                   unsigned short* __restrict__ ao) {
    __shared__ unsigned short Ks[64 * 72];     // [kv][d], stride 72 (144B, 16B aligned)
    __shared__ unsigned short Vs[64 * 72];     // [d][kv] (V transposed)
    __shared__ unsigned short Pw[4][16 * 72];  // per-wave P relay

    const int tid = threadIdx.x;
    const int l = tid & 63, w = tid >> 6;
    const int lm = l & 15, lk = l >> 4;
    const int bh = blockIdx.y;
    const int qbase = blockIdx.x * 64;

    // Q fragments (A-operand): lane holds Q[row=lm][d = half*32 + lk*8 ..+7]
    int qrow = qbase + w * 16 + lm;
    int qr = min(qrow, SEQ - 1);
    const unsigned short* qp = &qg[((size_t)bh * SEQ + qr) * HD + lk * 8];
    bf16x8 qf0 = *reinterpret_cast<const bf16x8*>(qp);
    bf16x8 qf1 = *reinterpret_cast<const bf16x8*>(qp + 32);

    f32x4 o[4];
#pragma unroll
    for (int jd = 0; jd < 4; ++jd) o[jd] = f32x4{0.f, 0.f, 0.f, 0.f};
    float mrun[4], lrun[4];
#pragma unroll
    for (int r = 0; r < 4; ++r) { mrun[r] = -INFINITY; lrun[r] = 0.f; }

    const int NT = (SEQ + 63) >> 6;   // 22
    for (int t = 0; t < NT; ++t) {
        // stage K tile [kv][d] and V^T tile [d][kv]
#pragma unroll
        for (int rr = 0; rr < 2; ++rr) {
            int flat = rr * 256 + tid;        // 0..511
            int row = flat >> 3;              // 0..63
            int c8 = (flat & 7) << 3;         // 0..56
            int kvg = min(t * 64 + row, SEQ - 1);
            short8 kv = *reinterpret_cast<const short8*>(&kg[((size_t)bh * SEQ + kvg) * HD + c8]);
            *reinterpret_cast<short8*>(&Ks[row * 72 + c8]) = kv;
            short8 vv = *reinterpret_cast<const short8*>(&vTg[((size_t)bh * HD + row) * NPAD + t * 64 + c8]);
            *reinterpret_cast<short8*>(&Vs[row * 72 + c8]) = vv;
        }
        __syncthreads();

        // S = Q K^T  (16 q-rows x 64 kv-cols per wave)
        f32x4 s[4];
#pragma unroll
        for (int j = 0; j < 4; ++j) {
            f32x4 z = {0.f, 0.f, 0.f, 0.f};
            bf16x8 k0 = *reinterpret_cast<const bf16x8*>(&Ks[(j * 16 + lm) * 72 + lk * 8]);
            bf16x8 k1 = *reinterpret_cast<const bf16x8*>(&Ks[(j * 16 + lm) * 72 + 32 + lk * 8]);
            z = MFMA(qf0, k0, z);
            z = MFMA(qf1, k1, z);
            s[j] = z;
        }

        // online softmax, per C-row r (q row = lk*4+r), reduce across 16-lane group
        float p[4][4];
        float sc[4];
#pragma unroll
        for (int r = 0; r < 4; ++r) {
            float tmax = -INFINITY;
#pragma unroll
            for (int j = 0; j < 4; ++j) {
                int kvg = t * 64 + j * 16 + lm;
                float sv = (kvg < SEQ) ? s[j][r] : -INFINITY;
                s[j][r] = sv;
                tmax = fmaxf(tmax, sv);
            }
            tmax = fmaxf(tmax, __shfl_xor(tmax, 1));
            tmax = fmaxf(tmax, __shfl_xor(tmax, 2));
            tmax = fmaxf(tmax, __shfl_xor(tmax, 4));
            tmax = fmaxf(tmax, __shfl_xor(tmax, 8));
            float mnew = fmaxf(mrun[r], tmax);
            float scale = __expf(mrun[r] - mnew);
            float psum = 0.f;
#pragma unroll
            for (int j = 0; j < 4; ++j) {
                float pv = __expf(s[j][r] - mnew);   // -inf -> 0
                p[j][r] = pv;
                psum += pv;
            }
            psum += __shfl_xor(psum, 1);
            psum += __shfl_xor(psum, 2);
            psum += __shfl_xor(psum, 4);
            psum += __shfl_xor(psum, 8);
            lrun[r] = lrun[r] * scale + psum;
            mrun[r] = mnew;
            sc[r] = scale;
        }
#pragma unroll
        for (int jd = 0; jd < 4; ++jd) {
            o[jd][0] *= sc[0]; o[jd][1] *= sc[1];
            o[jd][2] *= sc[2]; o[jd][3] *= sc[3];
        }

        // relay P through LDS (C layout -> A-operand layout)
#pragma unroll
        for (int r = 0; r < 4; ++r)
#pragma unroll
            for (int j = 0; j < 4; ++j)
                Pw[w][(lk * 4 + r) * 72 + j * 16 + lm] = f2bf(p[j][r]);

        bf16x8 pa0 = *reinterpret_cast<const bf16x8*>(&Pw[w][lm * 72 + lk * 8]);
        bf16x8 pa1 = *reinterpret_cast<const bf16x8*>(&Pw[w][lm * 72 + 32 + lk * 8]);
#pragma unroll
        for (int jd = 0; jd < 4; ++jd) {
            bf16x8 v0 = *reinterpret_cast<const bf16x8*>(&Vs[(jd * 16 + lm) * 72 + lk * 8]);
            bf16x8 v1 = *reinterpret_cast<const bf16x8*>(&Vs[(jd * 16 + lm) * 72 + 32 + lk * 8]);
            o[jd] = MFMA(pa0, v0, o[jd]);
            o[jd] = MFMA(pa1, v1, o[jd]);
        }
        __syncthreads();
    }

    // epilogue: normalize and write attn_out [b][n][h*64+d] bf16
    int b = bh >> 4, h = bh & 15;
#pragma unroll
    for (int r = 0; r < 4; ++r) {
        int q = qbase + w * 16 + lk * 4 + r;
        if (q >= SEQ) continue;
        float inv = 1.f / lrun[r];
#pragma unroll
        for (int jd = 0; jd < 4; ++jd) {
            ao[((size_t)b * SEQ + q) * DIMC + h * HD + jd * 16 + lm] = f2bf(o[jd][r] * inv);
        }
    }
}

extern "C" void kernel_launch(void* const* d_in, const int* in_sizes, int n_in,
                              void* d_out, int out_size, void* d_ws, size_t ws_size,
                              hipStream_t stream) {
    const float* x      = (const float*)d_in[0];
    const float* w_qkv  = (const float*)d_in[1];
    const float* b_qkv  = (const float*)d_in[2];
    const float* w_proj = (const float*)d_in[3];
    const float* b_proj = (const float*)d_in[4];
    float* out = (float*)d_out;

    char* ws = (char*)d_ws;
    unsigned short* xb     = (unsigned short*)ws; ws += (size_t)MROWS * DIMC * 2;
    unsigned short* wqkvT  = (unsigned short*)ws; ws += (size_t)3 * DIMC * DIMC * 2;
    unsigned short* wprojT = (unsigned short*)ws; ws += (size_t)DIMC * DIMC * 2;
    unsigned short* qg     = (unsigned short*)ws; ws += (size_t)64 * SEQ * HD * 2;
    unsigned short* kg     = (unsigned short*)ws; ws += (size_t)64 * SEQ * HD * 2;
    unsigned short* vTg    = (unsigned short*)ws; ws += (size_t)64 * HD * NPAD * 2;
    unsigned short* ao     = (unsigned short*)ws; ws += (size_t)MROWS * DIMC * 2;

    const int nvec = MROWS * DIMC / 8;   // 701440
    cast_x_kernel<<<(nvec + 255) / 256, 256, 0, stream>>>(x, xb, nvec);
    transpose_cast_kernel<<<dim3(3 * DIMC / 32, DIMC / 32), 256, 0, stream>>>(w_qkv, wqkvT, DIMC, 3 * DIMC);
    transpose_cast_kernel<<<dim3(DIMC / 32, DIMC / 32), 256, 0, stream>>>(w_proj, wprojT, DIMC, DIMC);
    zero_vpad_kernel<<<(64 * 64 * (NPAD - SEQ) + 255) / 256, 256, 0, stream>>>(vTg);

    gemm_bt_kernel<0><<<dim3(3 * DIMC / 128, (MROWS + 127) / 128), 256, 0, stream>>>(
        xb, wqkvT, MROWS, 3 * DIMC, DIMC, b_qkv, qg, kg, vTg, nullptr);

    attn_kernel<<<dim3((SEQ + 63) / 64, 64), 256, 0, stream>>>(qg, kg, vTg, ao);

    gemm_bt_kernel<1><<<dim3(DIMC / 128, (MROWS + 127) / 128), 256, 0, stream>>>(
        ao, wprojT, MROWS, DIMC, DIMC, b_proj, nullptr, nullptr, nullptr, out);
}

// Round 3
// 217.400 us; speedup vs baseline: 1.1535x; 1.1535x over previous
//
#include <hip/hip_runtime.h>
#include <stdint.h>
#include <math.h>

typedef __attribute__((ext_vector_type(8))) __bf16 bf16x8;
typedef __attribute__((ext_vector_type(4))) __bf16 bf16x4;
typedef __attribute__((ext_vector_type(4))) float f32x4;
typedef __attribute__((ext_vector_type(8))) short short8;

#define MFMA(a, b, c) __builtin_amdgcn_mfma_f32_16x16x32_bf16((a), (b), (c), 0, 0, 0)

constexpr int DIMC  = 1024;
constexpr int HEADS = 16;
constexpr int HD    = 64;
constexpr int BATCH = 4;
constexpr int SEQ   = 1370;
constexpr int MROWS = BATCH * SEQ;      // 5480
constexpr int NPAD  = 1408;             // 22*64
// QK scale folded with log2(e) so softmax runs in exp2 domain
constexpr float QK_SCALE = 0.125f * 1.44269504088896341f;

__device__ __forceinline__ unsigned short f2bf(float f) {
    union { float f; unsigned int u; } v; v.f = f;
    unsigned int r = (v.u + 0x7FFFu + ((v.u >> 16) & 1u)) >> 16;
    return (unsigned short)r;
}

__device__ __forceinline__ void gl2lds16(const unsigned short* g, unsigned short* l) {
    __builtin_amdgcn_global_load_lds(
        (const __attribute__((address_space(1))) unsigned int*)g,
        (__attribute__((address_space(3))) unsigned int*)l,
        16, 0, 0);
}

// ---------------- cast x -> bf16 (8 elems/thread) ----------------
__global__ void cast_x_kernel(const float* __restrict__ x, unsigned short* __restrict__ xb, int nvec) {
    int i = blockIdx.x * blockDim.x + threadIdx.x;
    if (i >= nvec) return;
    f32x4 a = reinterpret_cast<const f32x4*>(x)[2 * i];
    f32x4 b = reinterpret_cast<const f32x4*>(x)[2 * i + 1];
    short8 o;
    o[0] = (short)f2bf(a[0]); o[1] = (short)f2bf(a[1]);
    o[2] = (short)f2bf(a[2]); o[3] = (short)f2bf(a[3]);
    o[4] = (short)f2bf(b[0]); o[5] = (short)f2bf(b[1]);
    o[6] = (short)f2bf(b[2]); o[7] = (short)f2bf(b[3]);
    reinterpret_cast<short8*>(xb)[i] = o;
}

// ------------- cast + transpose weights: in[R][C] f32 -> out[C][R] bf16 -------------
__global__ __launch_bounds__(256) void transpose_cast_kernel(const float* __restrict__ in,
                                                             unsigned short* __restrict__ out,
                                                             int R, int C) {
    __shared__ float tile[32][33];
    int tx = threadIdx.x & 31, ty = threadIdx.x >> 5;   // 32 x 8
    int cbase = blockIdx.x * 32, rbase = blockIdx.y * 32;
#pragma unroll
    for (int rr = 0; rr < 4; ++rr) {
        int r = ty + rr * 8;
        tile[r][tx] = in[(size_t)(rbase + r) * C + cbase + tx];
    }
    __syncthreads();
#pragma unroll
    for (int rr = 0; rr < 4; ++rr) {
        int cr = ty + rr * 8;
        out[(size_t)(cbase + cr) * R + rbase + tx] = f2bf(tile[tx][cr]);
    }
}

// ------------- zero the vT column pad [SEQ..NPAD) so masked P*garbage can't NaN -------------
__global__ void zero_vpad_kernel(unsigned short* __restrict__ vTg) {
    int idx = blockIdx.x * blockDim.x + threadIdx.x;
    const int padw = NPAD - SEQ;                 // 38
    const int total = 64 * 64 * padw;
    if (idx >= total) return;
    int col = SEQ + idx % padw;
    int rowflat = idx / padw;                    // bh*64 + d
    vTg[(size_t)rowflat * NPAD + col] = 0;
}

// ---------------- bf16 GEMM: C[M,N] = A[M,K] * Bt[N,K]^T (+bias), fused epilogues ----------------
// Staging via global_load_lds width=16 into LINEAR [128][32] LDS tiles (m97 structure).
// EPI 0: scatter into q (scaled), k, vT buffers.  EPI 1: fp32 output + bias.
template <int EPI>
__global__ __launch_bounds__(256) void gemm_bt_kernel(const unsigned short* __restrict__ A,
                                                      const unsigned short* __restrict__ Bt,
                                                      int M, int N, int K,
                                                      const float* __restrict__ bias,
                                                      unsigned short* __restrict__ qg,
                                                      unsigned short* __restrict__ kg,
                                                      unsigned short* __restrict__ vTg,
                                                      float* __restrict__ outf) {
    __shared__ unsigned short As[128 * 32];   // linear, 64B per row
    __shared__ unsigned short Bs[128 * 32];
    const int tid = threadIdx.x;
    const int l = tid & 63, w = tid >> 6;
    const int wr = w >> 1, wc = w & 1;
    const int lm = l & 15, lk = l >> 4;
    const int brow = blockIdx.y * 128, bcol = blockIdx.x * 128;

    f32x4 acc[4][4];
#pragma unroll
    for (int i = 0; i < 4; ++i)
#pragma unroll
        for (int j = 0; j < 4; ++j) acc[i][j] = f32x4{0.f, 0.f, 0.f, 0.f};

    const int nkt = K >> 5;
    for (int kt = 0; kt < nkt; ++kt) {
        // stage A,B tiles: 2 chunks each, lane covers 16B; LDS dest linear = flat*16B
#pragma unroll
        for (int rr = 0; rr < 2; ++rr) {
            int flat = rr * 256 + tid;           // 0..511
            int row = flat >> 2;                 // 0..127
            int c8 = (flat & 3) << 3;            // 0,8,16,24
            int ga = min(brow + row, M - 1);
            gl2lds16(&A[(size_t)ga * K + kt * 32 + c8], &As[flat * 8]);
            int gb = bcol + row;                 // N is a multiple of 128
            gl2lds16(&Bt[(size_t)gb * K + kt * 32 + c8], &Bs[flat * 8]);
        }
        __syncthreads();
        bf16x8 af[4], bfr[4];
#pragma unroll
        for (int i = 0; i < 4; ++i)
            af[i] = *reinterpret_cast<const bf16x8*>(&As[(wr * 64 + i * 16 + lm) * 32 + lk * 8]);
#pragma unroll
        for (int j = 0; j < 4; ++j)
            bfr[j] = *reinterpret_cast<const bf16x8*>(&Bs[(wc * 64 + j * 16 + lm) * 32 + lk * 8]);
#pragma unroll
        for (int i = 0; i < 4; ++i)
#pragma unroll
            for (int j = 0; j < 4; ++j)
                acc[i][j] = MFMA(af[i], bfr[j], acc[i][j]);
        __syncthreads();
    }

    // epilogue: C layout per fragment -> row=(lk*4+r), col=lm
#pragma unroll
    for (int i = 0; i < 4; ++i) {
        int mbase = brow + wr * 64 + i * 16 + lk * 4;
#pragma unroll
        for (int j = 0; j < 4; ++j) {
            int col = bcol + wc * 64 + j * 16 + lm;
            float bv = bias[col];
#pragma unroll
            for (int r = 0; r < 4; ++r) {
                int m = mbase + r;
                if (m >= M) continue;
                float val = acc[i][j][r] + bv;
                if constexpr (EPI == 0) {
                    int which = col >> 10;          // 0:q 1:k 2:v
                    int head = (col >> 6) & 15;
                    int d = col & 63;
                    int b = m / SEQ;
                    int nseq = m - b * SEQ;
                    int bh = b * HEADS + head;
                    if (which == 0) {
                        qg[((size_t)bh * SEQ + nseq) * HD + d] = f2bf(val * QK_SCALE);
                    } else if (which == 1) {
                        kg[((size_t)bh * SEQ + nseq) * HD + d] = f2bf(val);
                    } else {
                        vTg[((size_t)bh * HD + d) * NPAD + nseq] = f2bf(val);
                    }
                } else {
                    outf[(size_t)m * DIMC + col] = val;
                }
            }
        }
    }
}

// ---------------- flash attention: 64 q-rows / block, KV tiles of 64 ----------------
// Swapped QK^T: S = mfma(K, Q) -> S[kv][q], each lane owns ONE q-row (q = lm)
// -> softmax reductions are in-lane + 2 shuffles, state is scalar per lane.
__global__ __launch_bounds__(256) void attn_kernel(const unsigned short* __restrict__ qg,
                                                   const unsigned short* __restrict__ kg,
                                                   const unsigned short* __restrict__ vTg,
                                                   unsigned short* __restrict__ ao) {
    __shared__ unsigned short Ks[64 * 72];     // [kv][d], stride 72
    __shared__ unsigned short Vs[64 * 72];     // [d][kv] (V transposed)
    __shared__ unsigned short Pw[4][16 * 72];  // per-wave P relay [q][kv]

    const int tid = threadIdx.x;
    const int l = tid & 63, w = tid >> 6;
    const int lm = l & 15, lk = l >> 4;
    const int bh = blockIdx.y;
    const int qbase = blockIdx.x * 64;

    // Q fragment: lane holds Q[q=lm][d=lk*8..]
    int qr = min(qbase + w * 16 + lm, SEQ - 1);
    const unsigned short* qp = &qg[((size_t)bh * SEQ + qr) * HD + lk * 8];
    bf16x8 qf0 = *reinterpret_cast<const bf16x8*>(qp);
    bf16x8 qf1 = *reinterpret_cast<const bf16x8*>(qp + 32);

    f32x4 o[4];
#pragma unroll
    for (int jd = 0; jd < 4; ++jd) o[jd] = f32x4{0.f, 0.f, 0.f, 0.f};
    float mrun = -INFINITY, lrun = 0.f;

    const int NT = (SEQ + 63) >> 6;   // 22
    for (int t = 0; t < NT; ++t) {
        // stage K tile [kv][d] and V^T tile [d][kv]
#pragma unroll
        for (int rr = 0; rr < 2; ++rr) {
            int flat = rr * 256 + tid;        // 0..511
            int row = flat >> 3;              // 0..63
            int c8 = (flat & 7) << 3;         // 0..56
            int kvg = min(t * 64 + row, SEQ - 1);
            short8 kv = *reinterpret_cast<const short8*>(&kg[((size_t)bh * SEQ + kvg) * HD + c8]);
            *reinterpret_cast<short8*>(&Ks[row * 72 + c8]) = kv;
            short8 vv = *reinterpret_cast<const short8*>(&vTg[((size_t)bh * HD + row) * NPAD + t * 64 + c8]);
            *reinterpret_cast<short8*>(&Vs[row * 72 + c8]) = vv;
        }
        __syncthreads();

        // S^T = K Q^T : s[j][r] = S[kv = j*16 + lk*4 + r][q = lm]
        f32x4 s[4];
#pragma unroll
        for (int j = 0; j < 4; ++j) {
            f32x4 z = {0.f, 0.f, 0.f, 0.f};
            bf16x8 k0 = *reinterpret_cast<const bf16x8*>(&Ks[(j * 16 + lm) * 72 + lk * 8]);
            bf16x8 k1 = *reinterpret_cast<const bf16x8*>(&Ks[(j * 16 + lm) * 72 + 32 + lk * 8]);
            z = MFMA(k0, qf0, z);
            z = MFMA(k1, qf1, z);
            s[j] = z;
        }

        // mask only in the tail tile
        if (t == NT - 1) {
#pragma unroll
            for (int j = 0; j < 4; ++j)
#pragma unroll
                for (int r = 0; r < 4; ++r) {
                    int kvg = t * 64 + j * 16 + lk * 4 + r;
                    if (kvg >= SEQ) s[j][r] = -INFINITY;
                }
        }

        // online softmax (scalar per lane; lane's q-row = lm), exp2 domain
        float tmax = s[0][0];
#pragma unroll
        for (int j = 0; j < 4; ++j)
#pragma unroll
            for (int r = 0; r < 4; ++r) tmax = fmaxf(tmax, s[j][r]);
        tmax = fmaxf(tmax, __shfl_xor(tmax, 16));
        tmax = fmaxf(tmax, __shfl_xor(tmax, 32));
        float mnew = fmaxf(mrun, tmax);
        float scale = exp2f(mrun - mnew);
        float p[4][4];
        float psum = 0.f;
#pragma unroll
        for (int j = 0; j < 4; ++j)
#pragma unroll
            for (int r = 0; r < 4; ++r) {
                float pv = exp2f(s[j][r] - mnew);
                p[j][r] = pv;
                psum += pv;
            }
        psum += __shfl_xor(psum, 16);
        psum += __shfl_xor(psum, 32);
        lrun = lrun * scale + psum;
        mrun = mnew;

        // rescale O: O-row q = lk*4+r needs scale from lane (lk*4+r)
        float sc[4];
#pragma unroll
        for (int r = 0; r < 4; ++r) sc[r] = __shfl(scale, lk * 4 + r);
#pragma unroll
        for (int jd = 0; jd < 4; ++jd) {
            o[jd][0] *= sc[0]; o[jd][1] *= sc[1];
            o[jd][2] *= sc[2]; o[jd][3] *= sc[3];
        }

        // relay P through LDS: Pw[q=lm][kv], packed 4xbf16 writes (kv contiguous)
#pragma unroll
        for (int j = 0; j < 4; ++j) {
            bf16x4 pk;
            pk[0] = (__bf16)p[j][0]; pk[1] = (__bf16)p[j][1];
            pk[2] = (__bf16)p[j][2]; pk[3] = (__bf16)p[j][3];
            *reinterpret_cast<bf16x4*>(&Pw[w][lm * 72 + j * 16 + lk * 4]) = pk;
        }

        bf16x8 pa0 = *reinterpret_cast<const bf16x8*>(&Pw[w][lm * 72 + lk * 8]);
        bf16x8 pa1 = *reinterpret_cast<const bf16x8*>(&Pw[w][lm * 72 + 32 + lk * 8]);
#pragma unroll
        for (int jd = 0; jd < 4; ++jd) {
            bf16x8 v0 = *reinterpret_cast<const bf16x8*>(&Vs[(jd * 16 + lm) * 72 + lk * 8]);
            bf16x8 v1 = *reinterpret_cast<const bf16x8*>(&Vs[(jd * 16 + lm) * 72 + 32 + lk * 8]);
            o[jd] = MFMA(pa0, v0, o[jd]);
            o[jd] = MFMA(pa1, v1, o[jd]);
        }
        __syncthreads();
    }

    // epilogue: normalize and write attn_out [b][n][h*64+d] bf16
    int b = bh >> 4, h = bh & 15;
    float linv = 1.f / lrun;
#pragma unroll
    for (int r = 0; r < 4; ++r) {
        int q = qbase + w * 16 + lk * 4 + r;
        float inv = __shfl(linv, lk * 4 + r);
        if (q >= SEQ) continue;
#pragma unroll
        for (int jd = 0; jd < 4; ++jd) {
            ao[((size_t)b * SEQ + q) * DIMC + h * HD + jd * 16 + lm] = f2bf(o[jd][r] * inv);
        }
    }
}

extern "C" void kernel_launch(void* const* d_in, const int* in_sizes, int n_in,
                              void* d_out, int out_size, void* d_ws, size_t ws_size,
                              hipStream_t stream) {
    const float* x      = (const float*)d_in[0];
    const float* w_qkv  = (const float*)d_in[1];
    const float* b_qkv  = (const float*)d_in[2];
    const float* w_proj = (const float*)d_in[3];
    const float* b_proj = (const float*)d_in[4];
    float* out = (float*)d_out;

    char* ws = (char*)d_ws;
    unsigned short* xb     = (unsigned short*)ws; ws += (size_t)MROWS * DIMC * 2;
    unsigned short* wqkvT  = (unsigned short*)ws; ws += (size_t)3 * DIMC * DIMC * 2;
    unsigned short* wprojT = (unsigned short*)ws; ws += (size_t)DIMC * DIMC * 2;
    unsigned short* qg     = (unsigned short*)ws; ws += (size_t)64 * SEQ * HD * 2;
    unsigned short* kg     = (unsigned short*)ws; ws += (size_t)64 * SEQ * HD * 2;
    unsigned short* vTg    = (unsigned short*)ws; ws += (size_t)64 * HD * NPAD * 2;
    unsigned short* ao     = (unsigned short*)ws; ws += (size_t)MROWS * DIMC * 2;

    const int nvec = MROWS * DIMC / 8;   // 701440
    cast_x_kernel<<<(nvec + 255) / 256, 256, 0, stream>>>(x, xb, nvec);
    transpose_cast_kernel<<<dim3(3 * DIMC / 32, DIMC / 32), 256, 0, stream>>>(w_qkv, wqkvT, DIMC, 3 * DIMC);
    transpose_cast_kernel<<<dim3(DIMC / 32, DIMC / 32), 256, 0, stream>>>(w_proj, wprojT, DIMC, DIMC);
    zero_vpad_kernel<<<(64 * 64 * (NPAD - SEQ) + 255) / 256, 256, 0, stream>>>(vTg);

    gemm_bt_kernel<0><<<dim3(3 * DIMC / 128, (MROWS + 127) / 128), 256, 0, stream>>>(
        xb, wqkvT, MROWS, 3 * DIMC, DIMC, b_qkv, qg, kg, vTg, nullptr);

    attn_kernel<<<dim3((SEQ + 63) / 64, 64), 256, 0, stream>>>(qg, kg, vTg, ao);

    gemm_bt_kernel<1><<<dim3(DIMC / 128, (MROWS + 127) / 128), 256, 0, stream>>>(
        ao, wprojT, MROWS, DIMC, DIMC, b_proj, nullptr, nullptr, nullptr, out);
}

// Round 4
// 209.877 us; speedup vs baseline: 1.1949x; 1.0358x over previous
//
#include <hip/hip_runtime.h>
#include <stdint.h>
#include <math.h>

typedef __attribute__((ext_vector_type(8))) __bf16 bf16x8;
typedef __attribute__((ext_vector_type(4))) __bf16 bf16x4;
typedef __attribute__((ext_vector_type(4))) float f32x4;
typedef __attribute__((ext_vector_type(8))) short short8;

#define MFMA(a, b, c) __builtin_amdgcn_mfma_f32_16x16x32_bf16((a), (b), (c), 0, 0, 0)

constexpr int DIMC  = 1024;
constexpr int HEADS = 16;
constexpr int HD    = 64;
constexpr int BATCH = 4;
constexpr int SEQ   = 1370;
constexpr int MROWS = BATCH * SEQ;      // 5480
constexpr int NPAD  = 1408;             // 22*64
// QK scale folded with log2(e) so softmax runs in exp2 domain
constexpr float QK_SCALE = 0.125f * 1.44269504088896341f;

__device__ __forceinline__ unsigned short f2bf(float f) {
    union { float f; unsigned int u; } v; v.f = f;
    unsigned int r = (v.u + 0x7FFFu + ((v.u >> 16) & 1u)) >> 16;
    return (unsigned short)r;
}

__device__ __forceinline__ void gl2lds16(const unsigned short* g, unsigned short* l) {
    __builtin_amdgcn_global_load_lds(
        (const __attribute__((address_space(1))) unsigned int*)g,
        (__attribute__((address_space(3))) unsigned int*)l,
        16, 0, 0);
}

// ---------------- cast x -> bf16 (8 elems/thread) ----------------
__global__ void cast_x_kernel(const float* __restrict__ x, unsigned short* __restrict__ xb, int nvec) {
    int i = blockIdx.x * blockDim.x + threadIdx.x;
    if (i >= nvec) return;
    f32x4 a = reinterpret_cast<const f32x4*>(x)[2 * i];
    f32x4 b = reinterpret_cast<const f32x4*>(x)[2 * i + 1];
    short8 o;
    o[0] = (short)f2bf(a[0]); o[1] = (short)f2bf(a[1]);
    o[2] = (short)f2bf(a[2]); o[3] = (short)f2bf(a[3]);
    o[4] = (short)f2bf(b[0]); o[5] = (short)f2bf(b[1]);
    o[6] = (short)f2bf(b[2]); o[7] = (short)f2bf(b[3]);
    reinterpret_cast<short8*>(xb)[i] = o;
}

// ------------- cast + transpose weights: in[R][C] f32 -> out[C][R] bf16 -------------
__global__ __launch_bounds__(256) void transpose_cast_kernel(const float* __restrict__ in,
                                                             unsigned short* __restrict__ out,
                                                             int R, int C) {
    __shared__ float tile[32][33];
    int tx = threadIdx.x & 31, ty = threadIdx.x >> 5;   // 32 x 8
    int cbase = blockIdx.x * 32, rbase = blockIdx.y * 32;
#pragma unroll
    for (int rr = 0; rr < 4; ++rr) {
        int r = ty + rr * 8;
        tile[r][tx] = in[(size_t)(rbase + r) * C + cbase + tx];
    }
    __syncthreads();
#pragma unroll
    for (int rr = 0; rr < 4; ++rr) {
        int cr = ty + rr * 8;
        out[(size_t)(cbase + cr) * R + rbase + tx] = f2bf(tile[tx][cr]);
    }
}

// ------------- zero the vT column pad [SEQ..NPAD) so masked P*garbage can't NaN -------------
__global__ void zero_vpad_kernel(unsigned short* __restrict__ vTg) {
    int idx = blockIdx.x * blockDim.x + threadIdx.x;
    const int padw = NPAD - SEQ;                 // 38
    const int total = 64 * 64 * padw;
    if (idx >= total) return;
    int col = SEQ + idx % padw;
    int rowflat = idx / padw;                    // bh*64 + d
    vTg[(size_t)rowflat * NPAD + col] = 0;
}

// ---------------- bf16 GEMM: C[M,N] = A[M,K] * Bt[N,K]^T (+bias), fused epilogues ----------------
// Staging via global_load_lds width=16 into LINEAR [128][32] LDS tiles (m97 structure).
// EPI 0: scatter into q (scaled), k, vT buffers.  EPI 1: fp32 output + bias.
template <int EPI>
__global__ __launch_bounds__(256) void gemm_bt_kernel(const unsigned short* __restrict__ A,
                                                      const unsigned short* __restrict__ Bt,
                                                      int M, int N, int K,
                                                      const float* __restrict__ bias,
                                                      unsigned short* __restrict__ qg,
                                                      unsigned short* __restrict__ kg,
                                                      unsigned short* __restrict__ vTg,
                                                      float* __restrict__ outf) {
    __shared__ unsigned short As[128 * 32];   // linear, 64B per row
    __shared__ unsigned short Bs[128 * 32];
    const int tid = threadIdx.x;
    const int l = tid & 63, w = tid >> 6;
    const int wr = w >> 1, wc = w & 1;
    const int lm = l & 15, lk = l >> 4;
    const int brow = blockIdx.y * 128, bcol = blockIdx.x * 128;

    f32x4 acc[4][4];
#pragma unroll
    for (int i = 0; i < 4; ++i)
#pragma unroll
        for (int j = 0; j < 4; ++j) acc[i][j] = f32x4{0.f, 0.f, 0.f, 0.f};

    const int nkt = K >> 5;
    for (int kt = 0; kt < nkt; ++kt) {
        // stage A,B tiles: 2 chunks each, lane covers 16B; LDS dest linear = flat*16B
#pragma unroll
        for (int rr = 0; rr < 2; ++rr) {
            int flat = rr * 256 + tid;           // 0..511
            int row = flat >> 2;                 // 0..127
            int c8 = (flat & 3) << 3;            // 0,8,16,24
            int ga = min(brow + row, M - 1);
            gl2lds16(&A[(size_t)ga * K + kt * 32 + c8], &As[flat * 8]);
            int gb = bcol + row;                 // N is a multiple of 128
            gl2lds16(&Bt[(size_t)gb * K + kt * 32 + c8], &Bs[flat * 8]);
        }
        __syncthreads();
        bf16x8 af[4], bfr[4];
#pragma unroll
        for (int i = 0; i < 4; ++i)
            af[i] = *reinterpret_cast<const bf16x8*>(&As[(wr * 64 + i * 16 + lm) * 32 + lk * 8]);
#pragma unroll
        for (int j = 0; j < 4; ++j)
            bfr[j] = *reinterpret_cast<const bf16x8*>(&Bs[(wc * 64 + j * 16 + lm) * 32 + lk * 8]);
#pragma unroll
        for (int i = 0; i < 4; ++i)
#pragma unroll
            for (int j = 0; j < 4; ++j)
                acc[i][j] = MFMA(af[i], bfr[j], acc[i][j]);
        __syncthreads();
    }

    // epilogue: C layout per fragment -> row=(lk*4+r), col=lm
#pragma unroll
    for (int i = 0; i < 4; ++i) {
        int mbase = brow + wr * 64 + i * 16 + lk * 4;
#pragma unroll
        for (int j = 0; j < 4; ++j) {
            int col = bcol + wc * 64 + j * 16 + lm;
            float bv = bias[col];
#pragma unroll
            for (int r = 0; r < 4; ++r) {
                int m = mbase + r;
                if (m >= M) continue;
                float val = acc[i][j][r] + bv;
                if constexpr (EPI == 0) {
                    int which = col >> 10;          // 0:q 1:k 2:v
                    int head = (col >> 6) & 15;
                    int d = col & 63;
                    int b = m / SEQ;
                    int nseq = m - b * SEQ;
                    int bh = b * HEADS + head;
                    if (which == 0) {
                        qg[((size_t)bh * SEQ + nseq) * HD + d] = f2bf(val * QK_SCALE);
                    } else if (which == 1) {
                        kg[((size_t)bh * SEQ + nseq) * HD + d] = f2bf(val);
                    } else {
                        vTg[((size_t)bh * HD + d) * NPAD + nseq] = f2bf(val);
                    }
                } else {
                    outf[(size_t)m * DIMC + col] = val;
                }
            }
        }
    }
}

// ---------------- flash attention: 64 q-rows / block, KV tiles of 64 ----------------
// Swapped QK^T: S = mfma(K, Q) -> S[kv][q], each lane owns ONE q-row (q = lm).
// T14: K/V of tile t+1 reg-loaded during compute of tile t (2x unrolled, 2 reg sets).
// T13: defer-max (THR=8 in exp2 domain). T5: setprio around MFMA clusters.
// XCD swizzle: 1408 blocks = 8 XCDs x 176; each XCD owns 8 heads' K/V (L2-resident).
__global__ __launch_bounds__(256) void attn_kernel(const unsigned short* __restrict__ qg,
                                                   const unsigned short* __restrict__ kg,
                                                   const unsigned short* __restrict__ vTg,
                                                   unsigned short* __restrict__ ao) {
    __shared__ unsigned short Ks[64 * 72];     // [kv][d], stride 72
    __shared__ unsigned short Vs[64 * 72];     // [d][kv] (V transposed)
    __shared__ unsigned short Pw[4][16 * 72];  // per-wave P relay [q][kv]

    const int tid = threadIdx.x;
    const int l = tid & 63, w = tid >> 6;
    const int lm = l & 15, lk = l >> 4;

    // XCD-aware bijective swizzle: hw block b (b%8 = XCD) -> work (b%8)*176 + b/8
    int wg = (blockIdx.x & 7) * 176 + (blockIdx.x >> 3);
    const int bh = wg / 22;            // 0..63
    const int qbase = (wg - bh * 22) * 64;

    // Q fragment: lane holds Q[q=lm][d=lk*8..]
    int qr = min(qbase + w * 16 + lm, SEQ - 1);
    const unsigned short* qp = &qg[((size_t)bh * SEQ + qr) * HD + lk * 8];
    bf16x8 qf0 = *reinterpret_cast<const bf16x8*>(qp);
    bf16x8 qf1 = *reinterpret_cast<const bf16x8*>(qp + 32);

    f32x4 o[4];
#pragma unroll
    for (int jd = 0; jd < 4; ++jd) o[jd] = f32x4{0.f, 0.f, 0.f, 0.f};
    float mrun = -INFINITY, lrun = 0.f;

    const int r0 = tid >> 3;                 // 0..31
    const int c8b = (tid & 7) << 3;          // 0..56
    const unsigned short* kbase = &kg[(size_t)bh * SEQ * HD];
    const unsigned short* vbase = &vTg[(size_t)bh * HD * NPAD];

    auto load_tile = [&](int t, short8* kr, short8* vr) {
#pragma unroll
        for (int rr = 0; rr < 2; ++rr) {
            int row = rr * 32 + r0;
            int kvg = min(t * 64 + row, SEQ - 1);
            kr[rr] = *reinterpret_cast<const short8*>(&kbase[(size_t)kvg * HD + c8b]);
            vr[rr] = *reinterpret_cast<const short8*>(&vbase[(size_t)row * NPAD + t * 64 + c8b]);
        }
    };
    auto write_tile = [&](const short8* kr, const short8* vr) {
#pragma unroll
        for (int rr = 0; rr < 2; ++rr) {
            int row = rr * 32 + r0;
            *reinterpret_cast<short8*>(&Ks[row * 72 + c8b]) = kr[rr];
            *reinterpret_cast<short8*>(&Vs[row * 72 + c8b]) = vr[rr];
        }
    };

    const int NT = (SEQ + 63) >> 6;   // 22

    auto compute_tile = [&](int t) {
        // S^T = K Q^T : s[j][r] = S[kv = j*16 + lk*4 + r][q = lm]
        f32x4 s[4];
        __builtin_amdgcn_s_setprio(1);
#pragma unroll
        for (int j = 0; j < 4; ++j) {
            f32x4 z = {0.f, 0.f, 0.f, 0.f};
            bf16x8 k0 = *reinterpret_cast<const bf16x8*>(&Ks[(j * 16 + lm) * 72 + lk * 8]);
            bf16x8 k1 = *reinterpret_cast<const bf16x8*>(&Ks[(j * 16 + lm) * 72 + 32 + lk * 8]);
            z = MFMA(k0, qf0, z);
            z = MFMA(k1, qf1, z);
            s[j] = z;
        }
        __builtin_amdgcn_s_setprio(0);

        // mask only in the tail tile
        if (t == NT - 1) {
#pragma unroll
            for (int j = 0; j < 4; ++j)
#pragma unroll
                for (int r = 0; r < 4; ++r) {
                    int kvg = t * 64 + j * 16 + lk * 4 + r;
                    if (kvg >= SEQ) s[j][r] = -INFINITY;
                }
        }

        // online softmax (scalar per lane; lane's q-row = lm), exp2 domain
        float tmax = s[0][0];
#pragma unroll
        for (int j = 0; j < 4; ++j)
#pragma unroll
            for (int r = 0; r < 4; ++r) tmax = fmaxf(tmax, s[j][r]);
        tmax = fmaxf(tmax, __shfl_xor(tmax, 16));
        tmax = fmaxf(tmax, __shfl_xor(tmax, 32));

        // T13 defer-max: skip rescale while tile max stays within 2^8 of running max
        if (!__all(tmax - mrun <= 8.0f)) {
            float mnew = fmaxf(mrun, tmax);
            float scale = exp2f(mrun - mnew);
            mrun = mnew;
            lrun *= scale;
            float sc[4];
#pragma unroll
            for (int r = 0; r < 4; ++r) sc[r] = __shfl(scale, lk * 4 + r);
#pragma unroll
            for (int jd = 0; jd < 4; ++jd) {
                o[jd][0] *= sc[0]; o[jd][1] *= sc[1];
                o[jd][2] *= sc[2]; o[jd][3] *= sc[3];
            }
        }

        float p[4][4];
        float psum = 0.f;
#pragma unroll
        for (int j = 0; j < 4; ++j)
#pragma unroll
            for (int r = 0; r < 4; ++r) {
                float pv = exp2f(s[j][r] - mrun);
                p[j][r] = pv;
                psum += pv;
            }
        psum += __shfl_xor(psum, 16);
        psum += __shfl_xor(psum, 32);
        lrun += psum;

        // relay P through LDS: Pw[q=lm][kv], packed 4xbf16 writes (kv contiguous)
#pragma unroll
        for (int j = 0; j < 4; ++j) {
            bf16x4 pk;
            pk[0] = (__bf16)p[j][0]; pk[1] = (__bf16)p[j][1];
            pk[2] = (__bf16)p[j][2]; pk[3] = (__bf16)p[j][3];
            *reinterpret_cast<bf16x4*>(&Pw[w][lm * 72 + j * 16 + lk * 4]) = pk;
        }

        bf16x8 pa0 = *reinterpret_cast<const bf16x8*>(&Pw[w][lm * 72 + lk * 8]);
        bf16x8 pa1 = *reinterpret_cast<const bf16x8*>(&Pw[w][lm * 72 + 32 + lk * 8]);
        __builtin_amdgcn_s_setprio(1);
#pragma unroll
        for (int jd = 0; jd < 4; ++jd) {
            bf16x8 v0 = *reinterpret_cast<const bf16x8*>(&Vs[(jd * 16 + lm) * 72 + lk * 8]);
            bf16x8 v1 = *reinterpret_cast<const bf16x8*>(&Vs[(jd * 16 + lm) * 72 + 32 + lk * 8]);
            o[jd] = MFMA(pa0, v0, o[jd]);
            o[jd] = MFMA(pa1, v1, o[jd]);
        }
        __builtin_amdgcn_s_setprio(0);
    };

    short8 krA[2], vrA[2], krB[2], vrB[2];
    load_tile(0, krA, vrA);
    for (int t = 0; t < NT; t += 2) {           // NT = 22 (even)
        write_tile(krA, vrA);
        __syncthreads();
        if (t + 1 < NT) load_tile(t + 1, krB, vrB);
        compute_tile(t);
        __syncthreads();

        write_tile(krB, vrB);
        __syncthreads();
        if (t + 2 < NT) load_tile(t + 2, krA, vrA);
        compute_tile(t + 1);
        __syncthreads();
    }

    // epilogue: normalize and write attn_out [b][n][h*64+d] bf16
    int b = bh >> 4, h = bh & 15;
    float linv = 1.f / lrun;
#pragma unroll
    for (int r = 0; r < 4; ++r) {
        int q = qbase + w * 16 + lk * 4 + r;
        float inv = __shfl(linv, lk * 4 + r);
        if (q >= SEQ) continue;
#pragma unroll
        for (int jd = 0; jd < 4; ++jd) {
            ao[((size_t)b * SEQ + q) * DIMC + h * HD + jd * 16 + lm] = f2bf(o[jd][r] * inv);
        }
    }
}

extern "C" void kernel_launch(void* const* d_in, const int* in_sizes, int n_in,
                              void* d_out, int out_size, void* d_ws, size_t ws_size,
                              hipStream_t stream) {
    const float* x      = (const float*)d_in[0];
    const float* w_qkv  = (const float*)d_in[1];
    const float* b_qkv  = (const float*)d_in[2];
    const float* w_proj = (const float*)d_in[3];
    const float* b_proj = (const float*)d_in[4];
    float* out = (float*)d_out;

    char* ws = (char*)d_ws;
    unsigned short* xb     = (unsigned short*)ws; ws += (size_t)MROWS * DIMC * 2;
    unsigned short* wqkvT  = (unsigned short*)ws; ws += (size_t)3 * DIMC * DIMC * 2;
    unsigned short* wprojT = (unsigned short*)ws; ws += (size_t)DIMC * DIMC * 2;
    unsigned short* qg     = (unsigned short*)ws; ws += (size_t)64 * SEQ * HD * 2;
    unsigned short* kg     = (unsigned short*)ws; ws += (size_t)64 * SEQ * HD * 2;
    unsigned short* vTg    = (unsigned short*)ws; ws += (size_t)64 * HD * NPAD * 2;
    unsigned short* ao     = (unsigned short*)ws; ws += (size_t)MROWS * DIMC * 2;

    const int nvec = MROWS * DIMC / 8;   // 701440
    cast_x_kernel<<<(nvec + 255) / 256, 256, 0, stream>>>(x, xb, nvec);
    transpose_cast_kernel<<<dim3(3 * DIMC / 32, DIMC / 32), 256, 0, stream>>>(w_qkv, wqkvT, DIMC, 3 * DIMC);
    transpose_cast_kernel<<<dim3(DIMC / 32, DIMC / 32), 256, 0, stream>>>(w_proj, wprojT, DIMC, DIMC);
    zero_vpad_kernel<<<(64 * 64 * (NPAD - SEQ) + 255) / 256, 256, 0, stream>>>(vTg);

    gemm_bt_kernel<0><<<dim3(3 * DIMC / 128, (MROWS + 127) / 128), 256, 0, stream>>>(
        xb, wqkvT, MROWS, 3 * DIMC, DIMC, b_qkv, qg, kg, vTg, nullptr);

    attn_kernel<<<dim3(22 * 64), 256, 0, stream>>>(qg, kg, vTg, ao);

    gemm_bt_kernel<1><<<dim3(DIMC / 128, (MROWS + 127) / 128), 256, 0, stream>>>(
        ao, wprojT, MROWS, DIMC, DIMC, b_proj, nullptr, nullptr, nullptr, out);
}